// Round 4
// baseline (262.070 us; speedup 1.0000x reference)
//
#include <hip/hip_runtime.h>
#include <stdint.h>

#define TT 512
#define BB 1024
#define NN 64

typedef __attribute__((ext_vector_type(8))) short short8;
typedef __attribute__((ext_vector_type(4))) float f32x4;

union W8 { uint32_t w[4]; short8 v; };

__device__ __forceinline__ uint32_t cvt_pk_bf16(float lo, float hi){
    uint32_t r;
    asm("v_cvt_pk_bf16_f32 %0, %1, %2" : "=v"(r) : "v"(lo), "v"(hi));
    return r;
}
// gfx950 cross-lane 16/32-group swaps (VALU, no LDS):
// swap32(a,b): a' = (a(q0),a(q1),b(q0),b(q1)); b' = (a(q2),a(q3),b(q2),b(q3))
// swap16(a,b): a' = (a(q0),b(q0),a(q2),b(q2)); b' = (a(q1),b(q1),a(q3),b(q3))
__device__ __forceinline__ void perm32swap(uint32_t &a, uint32_t &b){
    asm("v_permlane32_swap_b32 %0, %1" : "+v"(a), "+v"(b));
}
__device__ __forceinline__ void perm16swap(uint32_t &a, uint32_t &b){
    asm("v_permlane16_swap_b32 %0, %1" : "+v"(a), "+v"(b));
}

// Detect input integer widths (harness may canonicalize int64->int32, bool->int32).
__global__ void __launch_bounds__(64, 1)
detect_kernel(const uint32_t* __restrict__ tgt, const uint8_t* __restrict__ msk,
              int* __restrict__ flags) {
    if (threadIdx.x == 0) {
        uint32_t s = 0;
        for (int i = 0; i < 128; ++i) s |= tgt[2 * i + 1];
        flags[0] = (s == 0) ? 1 : 0;   // 1 => target is int64
        uint32_t mz = 0;
        for (int i = 0; i < 8; ++i) mz |= msk[4*i+1] | msk[4*i+2] | msk[4*i+3];
        flags[1] = (mz == 0) ? 1 : 0;  // 1 => mask is int32
    }
}

// Gold-path score: fully parallel over (t, b).
__global__ void __launch_bounds__(256)
score_kernel(const float* __restrict__ emit, const float* __restrict__ trans,
             const float* __restrict__ strans, const float* __restrict__ etrans,
             const void* __restrict__ target, const void* __restrict__ mask,
             const int* __restrict__ flags, float* __restrict__ out)
{
    const int idx = blockIdx.x * 256 + threadIdx.x;   // T*B threads
    const int t = idx >> 10, b = idx & (BB - 1);
    const int t64 = flags[0], m32 = flags[1];

    auto getm = [&](int tt) -> int {
        if (m32) return ((const int*)mask)[(size_t)tt * BB + b] != 0;
        else     return ((const uint8_t*)mask)[(size_t)tt * BB + b] != 0;
    };
    auto gett = [&](int tt) -> int {
        if (t64) return (int)((const long long*)target)[(size_t)tt * BB + b];
        else     return ((const int*)target)[(size_t)tt * BB + b];
    };

    const int m  = getm(t);
    const int tg = gett(t);
    float term = 0.f;
    if (m)      term += emit[((size_t)t * BB + b) * NN + tg];
    if (t == 0) term += strans[tg];
    if (t > 0 && m) term += trans[gett(t - 1) * NN + tg];
    const int mn = (t == TT - 1) ? 0 : getm(t + 1);
    if (m && !mn) term += etrans[tg];   // t == len-1 (contiguous prefix)

    #pragma unroll
    for (int off = 1; off < 64; off <<= 1) term += __shfl_xor(term, off);
    __shared__ float sred[4];
    const int wid = threadIdx.x >> 6, lane = threadIdx.x & 63;
    if (lane == 0) sred[wid] = term;
    __syncthreads();
    if (threadIdx.x == 0)
        atomicAdd(out, -(sred[0] + sred[1] + sred[2] + sred[3]) * (1.0f / (float)BB));
}

// Forward scan, MFMA + permlane relayout, freeze-free with per-chain logZ latch.
// Wave owns 16 chains. State S: D-layout, lane (q=lane>>4, c=lane&15),
// reg (mt,r) <-> S[state=16mt+4q+r][chain c] (HW-verified in R3).
__global__ void __launch_bounds__(64, 1)
crf_scan(const float* __restrict__ emit, const float* __restrict__ trans,
         const float* __restrict__ strans, const float* __restrict__ etrans,
         const void* __restrict__ mask, const int* __restrict__ flags,
         float* __restrict__ out)
{
    const int lane = threadIdx.x & 63;
    const int q = lane >> 4;
    const int c = lane & 15;
    const int b = (blockIdx.x << 4) + c;
    const int m32 = flags[1];

    // ---- per-chain length (contiguous-prefix mask), q-lanes split T ----
    int lp = 0;
    if (m32) {
        const int* mp = (const int*)mask;
        #pragma unroll 8
        for (int i = 0; i < 128; ++i)
            lp += (mp[(size_t)(q * 128 + i) * BB + b] != 0) ? 1 : 0;
    } else {
        const uint8_t* mp = (const uint8_t*)mask;
        #pragma unroll 8
        for (int i = 0; i < 128; ++i)
            lp += (mp[(size_t)(q * 128 + i) * BB + b] != 0) ? 1 : 0;
    }
    lp += __shfl_xor(lp, 16);
    lp += __shfl_xor(lp, 32);
    const int len = lp;
    int maxlen = len;
    #pragma unroll
    for (int off = 1; off < 64; off <<= 1)
        maxlen = max(maxlen, __shfl_xor(maxlen, off));

    // ---- A-operand: E^T tiles, E[j][n]=exp(trans[j][n]) (verified R3) ----
    short8 Ef[4][2];
    #pragma unroll
    for (int mt = 0; mt < 4; ++mt) {
        #pragma unroll
        for (int kt = 0; kt < 2; ++kt) {
            W8 u;
            #pragma unroll
            for (int jj = 0; jj < 8; jj += 2) {
                float f0 = __expf(trans[(size_t)(32*kt + 8*q + jj    ) * NN + 16*mt + c]);
                float f1 = __expf(trans[(size_t)(32*kt + 8*q + jj + 1) * NN + 16*mt + c]);
                u.w[jj >> 1] = cvt_pk_bf16(f0, f1);
            }
            Ef[mt][kt] = u.v;
        }
    }
    // exp(etrans) resident, for the extraction reduce
    float ee[4][4];
    #pragma unroll
    for (int mt = 0; mt < 4; ++mt)
        #pragma unroll
        for (int r = 0; r < 4; ++r)
            ee[mt][r] = __expf(etrans[16*mt + 4*q + r]);

    // ---- state init: S = exp(strans + emit[0]) ----
    f32x4 S[4];
    float m = 0.f;
    float lz = 0.f;                  // per-chain logZ latch
    #pragma unroll
    for (int mt = 0; mt < 4; ++mt) {
        f32x4 e0 = *(const f32x4*)(emit + (size_t)b * NN + 16*mt + 4*q);
        #pragma unroll
        for (int r = 0; r < 4; ++r)
            S[mt][r] = __expf(strans[16*mt + 4*q + r] + e0[r]);
    }

    // exact per-chain power-of-2 renorm (tree max -> v_max3 fusion)
    auto renorm = [&]() {
        float x0 = fmaxf(fmaxf(S[0][0], S[0][1]), fmaxf(S[0][2], S[0][3]));
        float x1 = fmaxf(fmaxf(S[1][0], S[1][1]), fmaxf(S[1][2], S[1][3]));
        float x2 = fmaxf(fmaxf(S[2][0], S[2][1]), fmaxf(S[2][2], S[2][3]));
        float x3 = fmaxf(fmaxf(S[3][0], S[3][1]), fmaxf(S[3][2], S[3][3]));
        float mx = fmaxf(fmaxf(x0, x1), fmaxf(x2, x3));
        mx = fmaxf(mx, __shfl_xor(mx, 16));
        mx = fmaxf(mx, __shfl_xor(mx, 32));
        int ex = (int)((__float_as_uint(mx) >> 23) & 0xffu) - 127;
        float sc = __uint_as_float((uint32_t)(127 - ex) << 23);   // exact 2^-ex
        #pragma unroll
        for (int mt = 0; mt < 4; ++mt)
            #pragma unroll
            for (int r = 0; r < 4; ++r)
                S[mt][r] *= sc;
        m += (float)ex * 0.6931471805599453f;
    };
    renorm();

    // latch logZ for chains whose length == t (S currently holds alpha after t positions)
    auto extract_if = [&](int t) {
        if (__any(len == t)) {
            float ve = 0.f;
            #pragma unroll
            for (int mt = 0; mt < 4; ++mt)
                #pragma unroll
                for (int r = 0; r < 4; ++r)
                    ve = __builtin_fmaf(S[mt][r], ee[mt][r], ve);
            ve += __shfl_xor(ve, 16);
            ve += __shfl_xor(ve, 32);
            float cand = m + __logf(ve);
            lz = (len == t) ? cand : lz;
        }
    };

    f32x4 rA[4], rB[4], ebA[4], ebB[4];
    auto load_raw = [&](int t, f32x4 (&R)[4]) {
        int tc = (t < TT) ? t : (TT - 1);
        const float* p = emit + ((size_t)tc * BB + b) * NN + 4*q;
        #pragma unroll
        for (int mt = 0; mt < 4; ++mt)
            R[mt] = *(const f32x4*)(p + 16*mt);
    };

    // one recurrence step: S = (E^T S) .* EBu; also exp-fill EBf from R, refill R
    auto substep = [&](int t, f32x4 (&R)[4], f32x4 (&EBu)[4], f32x4 (&EBf)[4]) {
        extract_if(t);
        // off-critical-path: exp for step t+1 (fills MFMA/permlane stall slots)
        #pragma unroll
        for (int mt = 0; mt < 4; ++mt)
            #pragma unroll
            for (int r = 0; r < 4; ++r)
                EBf[mt][r] = __expf(R[mt][r]);
        load_raw(t + 3, R);   // prefetch ~2 steps ahead

        // pack S to bf16 pairs
        uint32_t pk[4][2];
        #pragma unroll
        for (int mt = 0; mt < 4; ++mt) {
            pk[mt][0] = cvt_pk_bf16(S[mt][0], S[mt][1]);
            pk[mt][1] = cvt_pk_bf16(S[mt][2], S[mt][3]);
        }
        // D->B relayout via permlane swaps (replaces 16 ds_bpermute):
        // target B[kt].w at lane q = pk[2kt+(q>>1)][w&1] from q' = 2(q&1)+(w>>1)
        W8 B0, B1;
        {
            uint32_t a, bb;
            a = pk[0][0]; bb = pk[1][0];
            perm32swap(a, bb); perm16swap(a, bb);
            B0.w[0] = a; B0.w[2] = bb;
            a = pk[0][1]; bb = pk[1][1];
            perm32swap(a, bb); perm16swap(a, bb);
            B0.w[1] = a; B0.w[3] = bb;
            a = pk[2][0]; bb = pk[3][0];
            perm32swap(a, bb); perm16swap(a, bb);
            B1.w[0] = a; B1.w[2] = bb;
            a = pk[2][1]; bb = pk[3][1];
            perm32swap(a, bb); perm16swap(a, bb);
            B1.w[1] = a; B1.w[3] = bb;
        }
        // U = E^T * S  (8 MFMAs, 4 independent K-chains of depth 2)
        #pragma unroll
        for (int mt = 0; mt < 4; ++mt) {
            f32x4 acc = {0.f, 0.f, 0.f, 0.f};
            acc = __builtin_amdgcn_mfma_f32_16x16x32_bf16(Ef[mt][0], B0.v, acc, 0, 0, 0);
            acc = __builtin_amdgcn_mfma_f32_16x16x32_bf16(Ef[mt][1], B1.v, acc, 0, 0, 0);
            #pragma unroll
            for (int r = 0; r < 4; ++r)
                S[mt][r] = acc[r] * EBu[mt][r];   // emission multiply (no freeze)
        }
        if ((t & 3) == 0) renorm();
    };

    if (maxlen > 1) {
        load_raw(1, rA);            // borrow rA to build ebA(emit[1])
        #pragma unroll
        for (int mt = 0; mt < 4; ++mt)
            #pragma unroll
            for (int r = 0; r < 4; ++r)
                ebA[mt][r] = __expf(rA[mt][r]);
        load_raw(2, rA);
        load_raw(3, rB);
        int t = 1;
        while (true) {
            substep(t, rA, ebA, ebB);
            if (++t >= maxlen) break;
            substep(t, rB, ebB, ebA);
            if (++t >= maxlen) break;
        }
    }
    extract_if(maxlen);             // chains with len == maxlen

    // ---- reduce latched logZ over the wave's 16 chains ----
    float contrib = (q == 0) ? lz : 0.f;
    #pragma unroll
    for (int off = 1; off < 64; off <<= 1) contrib += __shfl_xor(contrib, off);
    if (lane == 0) atomicAdd(out, contrib * (1.0f / (float)BB));
}

extern "C" void kernel_launch(void* const* d_in, const int* in_sizes, int n_in,
                              void* d_out, int out_size, void* d_ws, size_t ws_size,
                              hipStream_t stream) {
    const float* emit   = (const float*)d_in[0];
    const float* trans  = (const float*)d_in[1];
    const float* strans = (const float*)d_in[2];
    const float* etrans = (const float*)d_in[3];
    const void*  target = d_in[4];
    const void*  mask   = d_in[5];
    int* flags = (int*)d_ws;

    hipMemsetAsync(d_out, 0, sizeof(float), stream);
    detect_kernel<<<1, 64, 0, stream>>>((const uint32_t*)target,
                                        (const uint8_t*)mask, flags);
    score_kernel<<<(TT * BB) / 256, 256, 0, stream>>>(emit, trans, strans, etrans,
                                                      target, mask, flags, (float*)d_out);
    crf_scan<<<BB / 16, 64, 0, stream>>>(emit, trans, strans, etrans,
                                         mask, flags, (float*)d_out);
}

// Round 7
// 214.529 us; speedup vs baseline: 1.2216x; 1.2216x over previous
//
#include <hip/hip_runtime.h>
#include <stdint.h>

#define TT 512
#define BB 1024
#define NN 64

typedef __attribute__((ext_vector_type(8))) short short8;
typedef __attribute__((ext_vector_type(4))) float f32x4;

union W8 { uint32_t w[4]; short8 v; };

__device__ __forceinline__ uint32_t cvt_pk_bf16(float lo, float hi){
    uint32_t r;
    asm("v_cvt_pk_bf16_f32 %0, %1, %2" : "=v"(r) : "v"(lo), "v"(hi));
    return r;
}
// gfx950 cross-lane 16/32-group swaps (VALU, no LDS) — HW-validated R4.
__device__ __forceinline__ void perm32swap(uint32_t &a, uint32_t &b){
    asm("v_permlane32_swap_b32 %0, %1" : "+v"(a), "+v"(b));
}
__device__ __forceinline__ void perm16swap(uint32_t &a, uint32_t &b){
    asm("v_permlane16_swap_b32 %0, %1" : "+v"(a), "+v"(b));
}

// Detect input integer widths (harness may canonicalize int64->int32, bool->int32).
__global__ void __launch_bounds__(64, 1)
detect_kernel(const uint32_t* __restrict__ tgt, const uint8_t* __restrict__ msk,
              int* __restrict__ flags) {
    if (threadIdx.x == 0) {
        uint32_t s = 0;
        for (int i = 0; i < 128; ++i) s |= tgt[2 * i + 1];
        flags[0] = (s == 0) ? 1 : 0;   // 1 => target is int64
        uint32_t mz = 0;
        for (int i = 0; i < 8; ++i) mz |= msk[4*i+1] | msk[4*i+2] | msk[4*i+3];
        flags[1] = (mz == 0) ? 1 : 0;  // 1 => mask is int32
    }
}

// Gold-path score: fully parallel over (t, b). (Unchanged — passed R1-R4.)
__global__ void __launch_bounds__(256)
score_kernel(const float* __restrict__ emit, const float* __restrict__ trans,
             const float* __restrict__ strans, const float* __restrict__ etrans,
             const void* __restrict__ target, const void* __restrict__ mask,
             const int* __restrict__ flags, float* __restrict__ out)
{
    const int idx = blockIdx.x * 256 + threadIdx.x;   // T*B threads
    const int t = idx >> 10, b = idx & (BB - 1);
    const int t64 = flags[0], m32 = flags[1];

    auto getm = [&](int tt) -> int {
        if (m32) return ((const int*)mask)[(size_t)tt * BB + b] != 0;
        else     return ((const uint8_t*)mask)[(size_t)tt * BB + b] != 0;
    };
    auto gett = [&](int tt) -> int {
        if (t64) return (int)((const long long*)target)[(size_t)tt * BB + b];
        else     return ((const int*)target)[(size_t)tt * BB + b];
    };

    const int m  = getm(t);
    const int tg = gett(t);
    float term = 0.f;
    if (m)      term += emit[((size_t)t * BB + b) * NN + tg];
    if (t == 0) term += strans[tg];
    if (t > 0 && m) term += trans[gett(t - 1) * NN + tg];
    const int mn = (t == TT - 1) ? 0 : getm(t + 1);
    if (m && !mn) term += etrans[tg];   // t == len-1 (contiguous prefix)

    #pragma unroll
    for (int off = 1; off < 64; off <<= 1) term += __shfl_xor(term, off);
    __shared__ float sred[4];
    const int wid = threadIdx.x >> 6, lane = threadIdx.x & 63;
    if (lane == 0) sred[wid] = term;
    __syncthreads();
    if (threadIdx.x == 0)
        atomicAdd(out, -(sred[0] + sred[1] + sred[2] + sred[3]) * (1.0f / (float)BB));
}

// Forward scan, single wave per 16 chains (R4-verified math) + depth-8
// register prefetch ring: load->use gap = 8 steps (~2400 cyc) >> HBM ~900 cyc.
__global__ void __launch_bounds__(64, 1)
crf_scan(const float* __restrict__ emit, const float* __restrict__ trans,
         const float* __restrict__ strans, const float* __restrict__ etrans,
         const void* __restrict__ mask, const int* __restrict__ flags,
         float* __restrict__ out)
{
    const int lane = threadIdx.x & 63;
    const int q = lane >> 4;
    const int c = lane & 15;
    const int b = (blockIdx.x << 4) + c;
    const int m32 = flags[1];

    // ---- per-chain length (contiguous-prefix mask), q-lanes split T ----
    int lp = 0;
    if (m32) {
        const int* mp = (const int*)mask;
        #pragma unroll 8
        for (int i = 0; i < 128; ++i)
            lp += (mp[(size_t)(q * 128 + i) * BB + b] != 0) ? 1 : 0;
    } else {
        const uint8_t* mp = (const uint8_t*)mask;
        #pragma unroll 8
        for (int i = 0; i < 128; ++i)
            lp += (mp[(size_t)(q * 128 + i) * BB + b] != 0) ? 1 : 0;
    }
    lp += __shfl_xor(lp, 16);
    lp += __shfl_xor(lp, 32);
    const int len = lp;
    int maxlen = len;
    #pragma unroll
    for (int off = 1; off < 64; off <<= 1)
        maxlen = max(maxlen, __shfl_xor(maxlen, off));
    const int NSTEP = maxlen - 1;

    // ---- A-operand: E^T tiles, E[j][n]=exp(trans[j][n]) (HW-verified R3/R4) ----
    short8 Ef[4][2];
    #pragma unroll
    for (int mt = 0; mt < 4; ++mt) {
        #pragma unroll
        for (int kt = 0; kt < 2; ++kt) {
            W8 u;
            #pragma unroll
            for (int jj = 0; jj < 8; jj += 2) {
                float f0 = __expf(trans[(size_t)(32*kt + 8*q + jj    ) * NN + 16*mt + c]);
                float f1 = __expf(trans[(size_t)(32*kt + 8*q + jj + 1) * NN + 16*mt + c]);
                u.w[jj >> 1] = cvt_pk_bf16(f0, f1);
            }
            Ef[mt][kt] = u.v;
        }
    }
    float ee[4][4];
    #pragma unroll
    for (int mt = 0; mt < 4; ++mt)
        #pragma unroll
        for (int r = 0; r < 4; ++r)
            ee[mt][r] = __expf(etrans[16*mt + 4*q + r]);

    // ---- state init: S = exp(strans + emit[0]) ----
    f32x4 S[4];
    float m = 0.f, lz = 0.f;
    #pragma unroll
    for (int mt = 0; mt < 4; ++mt) {
        f32x4 e0 = *(const f32x4*)(emit + (size_t)b * NN + 16*mt + 4*q);
        #pragma unroll
        for (int r = 0; r < 4; ++r)
            S[mt][r] = __expf(strans[16*mt + 4*q + r] + e0[r]);
    }

    auto renorm = [&]() {   // exact per-chain power-of-2 rescale
        float x0 = fmaxf(fmaxf(S[0][0], S[0][1]), fmaxf(S[0][2], S[0][3]));
        float x1 = fmaxf(fmaxf(S[1][0], S[1][1]), fmaxf(S[1][2], S[1][3]));
        float x2 = fmaxf(fmaxf(S[2][0], S[2][1]), fmaxf(S[2][2], S[2][3]));
        float x3 = fmaxf(fmaxf(S[3][0], S[3][1]), fmaxf(S[3][2], S[3][3]));
        float mx = fmaxf(fmaxf(x0, x1), fmaxf(x2, x3));
        mx = fmaxf(mx, __shfl_xor(mx, 16));
        mx = fmaxf(mx, __shfl_xor(mx, 32));
        int ex = (int)((__float_as_uint(mx) >> 23) & 0xffu) - 127;
        float sc = __uint_as_float((uint32_t)(127 - ex) << 23);   // exact 2^-ex
        #pragma unroll
        for (int mt = 0; mt < 4; ++mt)
            #pragma unroll
            for (int r = 0; r < 4; ++r)
                S[mt][r] *= sc;
        m += (float)ex * 0.6931471805599453f;
    };
    renorm();

    auto extract_if = [&](int t) {   // latch logZ for chains with len == t
        if (__any(len == t)) {
            float ve = 0.f;
            #pragma unroll
            for (int mt = 0; mt < 4; ++mt)
                #pragma unroll
                for (int r = 0; r < 4; ++r)
                    ve = __builtin_fmaf(S[mt][r], ee[mt][r], ve);
            ve += __shfl_xor(ve, 16);
            ve += __shfl_xor(ve, 32);
            float cand = m + __logf(ve);
            lz = (len == t) ? cand : lz;
        }
    };

    // ---- depth-8 register prefetch ring (static slot indices only) ----
    f32x4 R[8][4];
    auto prefetch = [&](int t, f32x4 (&Rk)[4]) {
        int tl = (t < TT) ? t : (TT - 1);
        const float* p = emit + ((size_t)tl << 16) + (size_t)b * NN + 4 * q;
        #pragma unroll
        for (int mt = 0; mt < 4; ++mt)
            Rk[mt] = *(const f32x4*)(p + 16 * mt);
    };

    auto dostep = [&](int t, f32x4 (&Rk)[4]) {
        extract_if(t);
        f32x4 EB[4];                       // exp(emit[t]) — the vmcnt wait point
        #pragma unroll
        for (int mt = 0; mt < 4; ++mt)
            #pragma unroll
            for (int r = 0; r < 4; ++r)
                EB[mt][r] = __expf(Rk[mt][r]);
        uint32_t pk[4][2];
        #pragma unroll
        for (int mt = 0; mt < 4; ++mt) {
            pk[mt][0] = cvt_pk_bf16(S[mt][0], S[mt][1]);
            pk[mt][1] = cvt_pk_bf16(S[mt][2], S[mt][3]);
        }
        W8 B0, B1;
        {
            uint32_t a, bb;
            a = pk[0][0]; bb = pk[1][0]; perm32swap(a, bb); perm16swap(a, bb);
            B0.w[0] = a; B0.w[2] = bb;
            a = pk[0][1]; bb = pk[1][1]; perm32swap(a, bb); perm16swap(a, bb);
            B0.w[1] = a; B0.w[3] = bb;
            a = pk[2][0]; bb = pk[3][0]; perm32swap(a, bb); perm16swap(a, bb);
            B1.w[0] = a; B1.w[2] = bb;
            a = pk[2][1]; bb = pk[3][1]; perm32swap(a, bb); perm16swap(a, bb);
            B1.w[1] = a; B1.w[3] = bb;
        }
        #pragma unroll
        for (int mt = 0; mt < 4; ++mt) {
            f32x4 acc = {0.f, 0.f, 0.f, 0.f};
            acc = __builtin_amdgcn_mfma_f32_16x16x32_bf16(Ef[mt][0], B0.v, acc, 0, 0, 0);
            acc = __builtin_amdgcn_mfma_f32_16x16x32_bf16(Ef[mt][1], B1.v, acc, 0, 0, 0);
            #pragma unroll
            for (int r = 0; r < 4; ++r)
                S[mt][r] = acc[r] * EB[mt][r];
        }
        if ((t & 3) == 0) renorm();        // same cadence as R4 (bit-identical)
    };

    if (NSTEP > 0) {
        #pragma unroll
        for (int k = 0; k < 8; ++k) prefetch(1 + k, R[k]);
        int t = 1;                          // t stays ≡ 1 (mod 8) in main loop
        while (t + 7 <= NSTEP) {
            #pragma unroll
            for (int k = 0; k < 8; ++k) {
                dostep(t + k, R[k]);
                prefetch(t + k + 8, R[k]);  // consumed 8 steps later
            }
            t += 8;
        }
        #pragma unroll
        for (int k = 0; k < 8; ++k) {       // tail: slots k hold steps t+k
            if (t + k <= NSTEP) dostep(t + k, R[k]);
        }
    }
    extract_if(maxlen);                     // chains with len == maxlen

    float contrib = (q == 0) ? lz : 0.f;
    #pragma unroll
    for (int off = 1; off < 64; off <<= 1) contrib += __shfl_xor(contrib, off);
    if (lane == 0) atomicAdd(out, contrib * (1.0f / (float)BB));
}

extern "C" void kernel_launch(void* const* d_in, const int* in_sizes, int n_in,
                              void* d_out, int out_size, void* d_ws, size_t ws_size,
                              hipStream_t stream) {
    const float* emit   = (const float*)d_in[0];
    const float* trans  = (const float*)d_in[1];
    const float* strans = (const float*)d_in[2];
    const float* etrans = (const float*)d_in[3];
    const void*  target = d_in[4];
    const void*  mask   = d_in[5];
    int* flags = (int*)d_ws;

    hipMemsetAsync(d_out, 0, sizeof(float), stream);
    detect_kernel<<<1, 64, 0, stream>>>((const uint32_t*)target,
                                        (const uint8_t*)mask, flags);
    score_kernel<<<(TT * BB) / 256, 256, 0, stream>>>(emit, trans, strans, etrans,
                                                      target, mask, flags, (float*)d_out);
    crf_scan<<<BB / 16, 64, 0, stream>>>(emit, trans, strans, etrans,
                                         mask, flags, (float*)d_out);
}